// Round 4
// baseline (331.161 us; speedup 1.0000x reference)
//
#include <hip/hip_runtime.h>
#include <stdint.h>

// Problem constants
#define B_   20
#define S_   4096
#define E_   256
#define NB_  32
#define M_   (B_ * S_)          // 81920 rows

// ws layout (bytes)
#define OFF_Q   41943040ull     // after xb region (M*256*2)
#define OFF_K   83886080ull
#define OFF_V   125829120ull    // vT bf16 [B][E][S]
#define OFF_WT  167772160ull    // WqT,WkT,WvT,WoT bf16, 131072 B each

typedef __attribute__((ext_vector_type(4))) float f32x4;
typedef __attribute__((ext_vector_type(8))) short short8;   // 8 x bf16
typedef __attribute__((ext_vector_type(4))) float float4v;
typedef __attribute__((ext_vector_type(4))) unsigned short us4;

__device__ __forceinline__ unsigned short f2bf(float f) {
  unsigned int u = __builtin_bit_cast(unsigned int, f);
  u += 0x7FFFu + ((u >> 16) & 1u);            // RNE
  return (unsigned short)(u >> 16);
}

__device__ __forceinline__ void glds16(const void* g, void* l) {
  __builtin_amdgcn_global_load_lds(
      (const __attribute__((address_space(1))) unsigned int*)g,
      (__attribute__((address_space(3))) unsigned int*)l, 16, 0, 0);
}

// ---------------- K0a: x fp32 -> bf16 ----------------
__global__ void k_convert_x(const float* __restrict__ x, unsigned short* __restrict__ xb) {
  size_t id = (size_t)blockIdx.x * 256 + threadIdx.x;
  float4v v = *(const float4v*)(x + id * 4);
  us4 o;
  o[0] = f2bf(v[0]); o[1] = f2bf(v[1]); o[2] = f2bf(v[2]); o[3] = f2bf(v[3]);
  *(us4*)(xb + id * 4) = o;
}

// ---------------- K0b: weights fp32 -> bf16, TRANSPOSED ([n][k]) ----------------
__global__ void k_convert_w(const float* __restrict__ Wq, const float* __restrict__ Wk,
                            const float* __restrict__ Wv, const float* __restrict__ Wo,
                            unsigned short* __restrict__ WT) {
  const float* src = (blockIdx.x == 0) ? Wq : (blockIdx.x == 1) ? Wk
                   : (blockIdx.x == 2) ? Wv : Wo;
  unsigned short* dst = WT + (size_t)blockIdx.x * 65536;
  int n = threadIdx.x;
  for (int k = 0; k < 256; ++k)
    dst[n * 256 + k] = f2bf(src[k * 256 + n]);
}

// ---------------- K1: QKV GEMM, 2-phase pipelined, XCD-chunked ----------------
// 128x128 tile, BK=64, 4 waves each 64x64 (4x4 of 16x16x32 frags).
// LDS XOR-swizzled (byte ^= (row&7)<<4) via pre-swizzled global source (G21).
// mat==2 (V) writes transposed vT[b][feat][s]. Epilogue goes through LDS so all
// global stores are coalesced 16B dwordx4 (was 2B/8B scattered).
__global__ __launch_bounds__(256, 2) void k_gemm(const unsigned short* __restrict__ A,
                                                 const unsigned short* __restrict__ WT,
                                                 unsigned short* __restrict__ qk,
                                                 unsigned short* __restrict__ vT) {
  __shared__ char Alds[2][16384];
  __shared__ char Blds[2][16384];
  // XCD-chunked: blocks sharing an A row-tile (same rt) land on the same XCD
  int g = blockIdx.x;
  int xcd = g & 7, idx = g >> 3;
  int rt = xcd * 80 + idx / 6;                 // 640 row-tiles, 80 per XCD
  int ct = idx % 6;
  int mat = ct >> 1;
  int col0 = (ct & 1) * 128;

  int tid = threadIdx.x, w = tid >> 6, l = tid & 63;
  int wr = (w >> 1) * 64, wc = (w & 1) * 64;
  int hi16 = (l >> 4) * 16;

  const char* Ab = (const char*)A + (size_t)rt * 128 * 512;
  const char* Bb = (const char*)(WT + (size_t)mat * 65536) + (size_t)col0 * 512;

  auto STAGE = [&](int bufi, int s) {
    int k0b = s * 128;
#pragma unroll
    for (int j8 = 0; j8 < 4; ++j8) {
      int d = (j8 * 256 + tid) * 16;
      int row = d >> 7;
      int cx = (d & 127) ^ ((row & 7) << 4);
      glds16(Ab + (size_t)row * 512 + k0b + cx, Alds[bufi] + d);
      glds16(Bb + (size_t)row * 512 + k0b + cx, Blds[bufi] + d);
    }
  };

  f32x4 acc[4][4] = {};
  STAGE(0, 0);

  for (int s = 0; s < 4; ++s) {
    int cur = s & 1;
    if (s < 3) {
      STAGE(cur ^ 1, s + 1);
      asm volatile("s_waitcnt vmcnt(8)" ::: "memory");   // current stage's 8 loads landed
    } else {
      asm volatile("s_waitcnt vmcnt(0)" ::: "memory");
    }
    __builtin_amdgcn_sched_barrier(0);
    __builtin_amdgcn_s_barrier();
#pragma unroll
    for (int ks = 0; ks < 2; ++ks) {
      short8 a[4], bb[4];
#pragma unroll
      for (int i = 0; i < 4; ++i) {
        int ra = wr + 16 * i + (l & 15);
        a[i] = *(const short8*)(Alds[cur] + ra * 128 + ((ks * 64 + hi16) ^ ((ra & 7) << 4)));
        int rb = wc + 16 * i + (l & 15);
        bb[i] = *(const short8*)(Blds[cur] + rb * 128 + ((rb & 7) << 4 ^ (ks * 64 + hi16)));
      }
      __builtin_amdgcn_s_setprio(1);
#pragma unroll
      for (int i = 0; i < 4; ++i)
#pragma unroll
        for (int j = 0; j < 4; ++j)
          acc[i][j] = __builtin_amdgcn_mfma_f32_16x16x32_bf16(a[i], bb[j], acc[i][j], 0, 0, 0);
      __builtin_amdgcn_s_setprio(0);
    }
    asm volatile("s_waitcnt lgkmcnt(0)" ::: "memory");
    __builtin_amdgcn_sched_barrier(0);
    __builtin_amdgcn_s_barrier();                        // buffer free for next STAGE
  }

  // ---- epilogue via LDS: tile 128x128 bf16 = 32 KB in Alds (free now) ----
  // C/D layout: col = lane&15, row = (lane>>4)*4 + r  [m89]
  char* E = &Alds[0][0];
  if (mat < 2) {
    // LDS[row s_local][col feat] rows of 256 B, swizzled
#pragma unroll
    for (int i = 0; i < 4; ++i)
#pragma unroll
      for (int j = 0; j < 4; ++j)
#pragma unroll
        for (int r = 0; r < 4; ++r) {
          int rowL = wr + 16 * i + (l >> 4) * 4 + r;
          int colL = wc + 16 * j + (l & 15);
          *(unsigned short*)(E + rowL * 256 + ((2 * colL) ^ ((rowL & 7) << 4))) =
              f2bf(acc[i][j][r]);
        }
  } else {
    // transposed: LDS[feat][s_local]
#pragma unroll
    for (int i = 0; i < 4; ++i)
#pragma unroll
      for (int j = 0; j < 4; ++j)
#pragma unroll
        for (int r = 0; r < 4; ++r) {
          int rowL = wr + 16 * i + (l >> 4) * 4 + r;      // s_local
          int colL = wc + 16 * j + (l & 15);              // feat
          *(unsigned short*)(E + colL * 256 + ((2 * rowL) ^ ((colL & 7) << 4))) =
              f2bf(acc[i][j][r]);
        }
  }
  __syncthreads();
  // coalesced read-out: thread t covers half a 256B LDS row
  int o = tid >> 1, h = tid & 1;
  char* gdst;
  if (mat < 2) {
    gdst = (char*)(qk + (size_t)mat * M_ * 256) + (size_t)(rt * 128 + o) * 512 +
           (size_t)col0 * 2 + h * 128;
  } else {
    int b = rt >> 5;
    gdst = (char*)vT + (size_t)(b * 256 + col0 + o) * 8192 + (size_t)(rt & 31) * 256 + h * 128;
  }
#pragma unroll
  for (int i = 0; i < 8; ++i) {
    short8 v = *(const short8*)(E + o * 256 + ((h * 128 + i * 16) ^ ((o & 7) << 4)));
    *(short8*)(gdst + i * 16) = v;
  }
}

// ---------------- K2: block-local attention + fused out-proj ----------------
// 1280 blocks: (b,n,half). 4 waves x 16 q-rows. Pipelined K/V phases (counted vmcnt);
// softmax without max-sub (|logit| < ~0.6, exact by shift-invariance); padded edge
// chunks contribute exp(0)=1 per key (dsum preinit). Epilogue: O -> LDS (bf16),
// O @ Wo + bias computed in-kernel (WoT staged from L2), fp32 out written at the
// permuted rows f = n*2560 + b*128 + half*64 + q (contiguous 64-row span).
__global__ __launch_bounds__(256, 2) void k_attn(const unsigned short* __restrict__ q,
                                                 const unsigned short* __restrict__ k,
                                                 const unsigned short* __restrict__ vT,
                                                 const unsigned short* __restrict__ WT,
                                                 const float* __restrict__ bo,
                                                 float* __restrict__ out) {
  __shared__ char kb2[2][32768];    // K [64][256] / Vt [256][64] / O [64][256] / WoT chunk
  __shared__ char pl[64 * 144];     // P [64 rows][64 keys] bf16, row stride 144 B

  int g = blockIdx.x;
  int xcd = g & 7, idx = g >> 3;                 // 160 per XCD
  int nbid = xcd * 80 + (idx >> 1);
  int half = idx & 1;
  int b = nbid >> 5, n = nbid & 31;
  int tid = threadIdx.x, w = tid >> 6, l = tid & 63;
  int hi16 = (l >> 4) * 16;

  int rowbase = b * 4096 + n * 128 + half * 64 + w * 16;
  const char* qrow = (const char*)q + (size_t)(rowbase + (l & 15)) * 512;
  short8 qf[8];
#pragma unroll
  for (int ks = 0; ks < 8; ++ks) qf[ks] = *(const short8*)(qrow + ks * 64 + hi16);

  f32x4 zero4 = {0.f, 0.f, 0.f, 0.f};
  f32x4 oacc[16];
#pragma unroll
  for (int fj = 0; fj < 16; ++fj) oacc[fj] = zero4;
  float einit = (n == 0 || n == 31) ? 8.0f : 0.0f;   // 2 padded chunks * 4 keys/lane
  float dsum[4] = {einit, einit, einit, einit};

  const char* kbase = (const char*)k + (size_t)b * 4096 * 512;
  const char* vtb   = (const char*)vT + (size_t)b * 256 * 8192;
  const char* woT   = (const char*)(WT + 3 * 65536);

  int c0 = (n == 0) ? 2 : 0;                     // valid chunk range (contiguous)
  int c1 = (n == 31) ? 3 : 5;
  int P = (c1 - c0 + 1) * 2;                     // 8 or 12 phases

  auto STAGE = [&](int bufi, int p) {
    int c = c0 + (p >> 1);
    int kg = (n + (c >> 1) - 1) * 128 + (c & 1) * 64;
    char* dst = kb2[bufi];
    if ((p & 1) == 0) {                          // K chunk: [64 keys][256 feats]
#pragma unroll
      for (int j8 = 0; j8 < 8; ++j8) {
        int d = (j8 * 256 + tid) * 16;
        int key = d >> 9;
        int f2 = (d & 511) ^ ((key & 7) << 4);
        glds16(kbase + (size_t)(kg + key) * 512 + f2, dst + d);
      }
    } else {                                     // Vt chunk: [256 feats][64 keys]
#pragma unroll
      for (int j8 = 0; j8 < 8; ++j8) {
        int d = (j8 * 256 + tid) * 16;
        int feat = d >> 7;
        int kx = (d & 127) ^ ((feat & 7) << 4);
        glds16(vtb + (size_t)feat * 8192 + (size_t)kg * 2 + kx, dst + d);
      }
    }
  };

  STAGE(0, 0);

  for (int p = 0; p < P; ++p) {
    int cur = p & 1;
    if (p + 1 < P) {
      STAGE(cur ^ 1, p + 1);
      asm volatile("s_waitcnt vmcnt(8)" ::: "memory");
    } else {
      asm volatile("s_waitcnt vmcnt(0)" ::: "memory");
    }
    __builtin_amdgcn_sched_barrier(0);
    __builtin_amdgcn_s_barrier();

    const char* kv = kb2[cur];
    if ((p & 1) == 0) {
      // QK^T /16, exp, denom, P -> LDS
#pragma unroll
      for (int j = 0; j < 4; ++j) {
        f32x4 s = zero4;
        int key = 16 * j + (l & 15);
        int kb0 = key * 512, km = (key & 7) << 4;
        __builtin_amdgcn_s_setprio(1);
#pragma unroll
        for (int ks = 0; ks < 8; ++ks) {
          short8 kf = *(const short8*)(kv + kb0 + ((ks * 64 + hi16) ^ km));
          s = __builtin_amdgcn_mfma_f32_16x16x32_bf16(qf[ks], kf, s, 0, 0, 0);
        }
        __builtin_amdgcn_s_setprio(0);
#pragma unroll
        for (int r = 0; r < 4; ++r) {
          float pv = __expf(s[r] * 0.0625f);
          dsum[r] += pv;
          int prow = w * 16 + (l >> 4) * 4 + r;
          *(unsigned short*)(pl + prow * 144 + key * 2) = f2bf(pv);
        }
      }
    } else {
      // O += P * V
#pragma unroll
      for (int ks2 = 0; ks2 < 2; ++ks2) {
        short8 pa = *(const short8*)(pl + (w * 16 + (l & 15)) * 144 + ks2 * 64 + hi16);
        __builtin_amdgcn_s_setprio(1);
#pragma unroll
        for (int fj = 0; fj < 16; ++fj) {
          int feat = 16 * fj + (l & 15);
          short8 vf = *(const short8*)(kv + feat * 128 + ((ks2 * 64 + hi16) ^ ((feat & 7) << 4)));
          oacc[fj] = __builtin_amdgcn_mfma_f32_16x16x32_bf16(pa, vf, oacc[fj], 0, 0, 0);
        }
        __builtin_amdgcn_s_setprio(0);
      }
    }
    asm volatile("s_waitcnt lgkmcnt(0)" ::: "memory");
    __builtin_amdgcn_sched_barrier(0);
    __builtin_amdgcn_s_barrier();
  }

  // ---- softmax denominator ----
#pragma unroll
  for (int r = 0; r < 4; ++r) {
    float t = dsum[r];
    t += __shfl_xor(t, 1); t += __shfl_xor(t, 2);
    t += __shfl_xor(t, 4); t += __shfl_xor(t, 8);
    dsum[r] = 1.0f / t;
  }

  // ---- fused out-proj: O(bf16) -> kb2[0]; WoT chunks -> kb2[1]; out = O@Wo + bo ----
  // O LDS: [64 q][256 feat] rows 512 B, swizzled. Each wave writes/reads its own rows.
  char* OL = kb2[0];
#pragma unroll
  for (int fj = 0; fj < 16; ++fj) {
    int c2 = 2 * (16 * fj + (l & 15));
#pragma unroll
    for (int r = 0; r < 4; ++r) {
      int qr = w * 16 + (l >> 4) * 4 + r;
      *(unsigned short*)(OL + qr * 512 + (c2 ^ ((qr & 7) << 4))) =
          f2bf(oacc[fj][r] * dsum[r]);
    }
  }

  auto STAGE_WO = [&](int kc) {                  // WoT[n][k] chunk: [256 n][128 B]
#pragma unroll
    for (int j8 = 0; j8 < 8; ++j8) {
      int d = (j8 * 256 + tid) * 16;
      int nrow = d >> 7;
      int kx = (d & 127) ^ ((nrow & 7) << 4);
      glds16(woT + (size_t)nrow * 512 + kc * 128 + kx, kb2[1] + d);
    }
  };

  f32x4 acc2[16];
#pragma unroll
  for (int j = 0; j < 16; ++j) acc2[j] = zero4;

  STAGE_WO(0);
  for (int kc = 0; kc < 4; ++kc) {
    asm volatile("s_waitcnt vmcnt(0)" ::: "memory");
    __builtin_amdgcn_sched_barrier(0);
    __builtin_amdgcn_s_barrier();
#pragma unroll
    for (int kstep = 0; kstep < 2; ++kstep) {
      int qr = w * 16 + (l & 15);
      short8 af = *(const short8*)(OL + qr * 512 +
                    ((kc * 128 + kstep * 64 + hi16) ^ ((qr & 7) << 4)));
      __builtin_amdgcn_s_setprio(1);
#pragma unroll
      for (int j = 0; j < 16; ++j) {
        int nr = 16 * j + (l & 15);
        short8 bf = *(const short8*)(kb2[1] + nr * 128 +
                      ((kstep * 64 + hi16) ^ ((nr & 7) << 4)));
        acc2[j] = __builtin_amdgcn_mfma_f32_16x16x32_bf16(af, bf, acc2[j], 0, 0, 0);
      }
      __builtin_amdgcn_s_setprio(0);
    }
    asm volatile("s_waitcnt lgkmcnt(0)" ::: "memory");
    __builtin_amdgcn_sched_barrier(0);
    __builtin_amdgcn_s_barrier();
    if (kc < 3) STAGE_WO(kc + 1);
  }

  // out rows f = n*2560 + b*128 + half*64 + q  (contiguous 64-row span)
  int f0 = n * 2560 + b * 128 + half * 64 + w * 16 + (l >> 4) * 4;
#pragma unroll
  for (int j = 0; j < 16; ++j) {
    int col = 16 * j + (l & 15);
    float bj = bo[col];
#pragma unroll
    for (int r = 0; r < 4; ++r)
      out[(size_t)(f0 + r) * 256 + col] = acc2[j][r] + bj;
  }
}

// ---------------- launch ----------------
extern "C" void kernel_launch(void* const* d_in, const int* in_sizes, int n_in,
                              void* d_out, int out_size, void* d_ws, size_t ws_size,
                              hipStream_t stream) {
  (void)in_sizes; (void)n_in; (void)out_size; (void)ws_size;
  const float* x  = (const float*)d_in[0];
  const float* Wq = (const float*)d_in[1];
  const float* Wk = (const float*)d_in[2];
  const float* Wv = (const float*)d_in[3];
  const float* Wo = (const float*)d_in[4];
  const float* bo = (const float*)d_in[5];

  char* ws = (char*)d_ws;
  unsigned short* xb = (unsigned short*)ws;
  unsigned short* qb = (unsigned short*)(ws + OFF_Q);
  unsigned short* kb = (unsigned short*)(ws + OFF_K);
  unsigned short* vT = (unsigned short*)(ws + OFF_V);
  unsigned short* WT = (unsigned short*)(ws + OFF_WT);

  k_convert_x<<<20480, 256, 0, stream>>>(x, xb);
  k_convert_w<<<4, 256, 0, stream>>>(Wq, Wk, Wv, Wo, WT);
  k_gemm<<<3840, 256, 0, stream>>>(xb, WT, qb, vT);          // q,k row-major; v -> vT
  k_attn<<<1280, 256, 0, stream>>>(qb, kb, vT, WT, bo, (float*)d_out);
}

// Round 5
// 293.327 us; speedup vs baseline: 1.1290x; 1.1290x over previous
//
#include <hip/hip_runtime.h>
#include <stdint.h>

// Problem constants
#define B_   20
#define S_   4096
#define E_   256
#define NB_  32
#define M_   (B_ * S_)          // 81920 rows

// ws layout (bytes)
#define OFF_Q   41943040ull     // after xb region (M*256*2)
#define OFF_K   83886080ull
#define OFF_V   125829120ull    // vT bf16 [B][E][S]
#define OFF_WT  167772160ull    // WqT,WkT,WvT,WoT bf16, 131072 B each

typedef __attribute__((ext_vector_type(4))) float f32x4;
typedef __attribute__((ext_vector_type(8))) short short8;   // 8 x bf16
typedef __attribute__((ext_vector_type(4))) float float4v;
typedef __attribute__((ext_vector_type(4))) unsigned short us4;

__device__ __forceinline__ unsigned short f2bf(float f) {
  unsigned int u = __builtin_bit_cast(unsigned int, f);
  u += 0x7FFFu + ((u >> 16) & 1u);            // RNE
  return (unsigned short)(u >> 16);
}

__device__ __forceinline__ void glds16(const void* g, void* l) {
  __builtin_amdgcn_global_load_lds(
      (const __attribute__((address_space(1))) unsigned int*)g,
      (__attribute__((address_space(3))) unsigned int*)l, 16, 0, 0);
}

// ---------------- K0a: x fp32 -> bf16 ----------------
__global__ void k_convert_x(const float* __restrict__ x, unsigned short* __restrict__ xb) {
  size_t id = (size_t)blockIdx.x * 256 + threadIdx.x;
  float4v v = *(const float4v*)(x + id * 4);
  us4 o;
  o[0] = f2bf(v[0]); o[1] = f2bf(v[1]); o[2] = f2bf(v[2]); o[3] = f2bf(v[3]);
  *(us4*)(xb + id * 4) = o;
}

// ---------------- K0b: weights fp32 -> bf16 TRANSPOSED, tiled ----------------
// 64 blocks = 4 matrices x 16 (64x64) tiles. Coalesced fp32 reads, LDS transpose,
// coalesced 16B bf16 writes. (Old version: 4 blocks, 2B stores at 512B stride.)
__global__ void k_convert_w(const float* __restrict__ Wq, const float* __restrict__ Wk,
                            const float* __restrict__ Wv, const float* __restrict__ Wo,
                            unsigned short* __restrict__ WT) {
  __shared__ float T[64][65];                    // +1 pad
  int g = blockIdx.x;
  int m = g >> 4, t = g & 15;
  int k0 = (t >> 2) * 64, n0 = (t & 3) * 64;
  const float* src = (m == 0) ? Wq : (m == 1) ? Wk : (m == 2) ? Wv : Wo;
  unsigned short* dst = WT + (size_t)m * 65536;
  int tid = threadIdx.x;
#pragma unroll
  for (int it = 0; it < 4; ++it) {               // read 64x64 fp32, coalesced float4
    int idx = it * 256 + tid;                    // float4 index 0..1023
    int kr = idx >> 4, nc = idx & 15;
    float4v v = *(const float4v*)(src + (size_t)(k0 + kr) * 256 + n0 + nc * 4);
    T[kr][nc * 4 + 0] = v[0]; T[kr][nc * 4 + 1] = v[1];
    T[kr][nc * 4 + 2] = v[2]; T[kr][nc * 4 + 3] = v[3];
  }
  __syncthreads();
#pragma unroll
  for (int it = 0; it < 2; ++it) {               // write transposed bf16, 16B coalesced
    int idx = it * 256 + tid;                    // 0..511
    int nr = idx >> 3, kc = idx & 7;
    short8 o;
#pragma unroll
    for (int e = 0; e < 8; ++e) o[e] = (short)f2bf(T[kc * 8 + e][nr]);
    *(short8*)(dst + (size_t)(n0 + nr) * 256 + k0 + kc * 8) = o;
  }
}

// ---------------- K1: QKV GEMM, 2-phase pipelined, XCD-chunked ----------------
// 128x128 tile, BK=64, 4 waves each 64x64 (4x4 of 16x16x32 frags).
// LDS XOR-swizzled (byte ^= (row&7)<<4) via pre-swizzled global source (G21).
// mat==2 (V) writes transposed vT[b][feat][s]. Direct-store epilogue (r3 form —
// the r4 LDS-transpose epilogue was a ~40us regression).
__global__ __launch_bounds__(256, 2) void k_gemm(const unsigned short* __restrict__ A,
                                                 const unsigned short* __restrict__ WT,
                                                 unsigned short* __restrict__ qk,
                                                 unsigned short* __restrict__ vT) {
  __shared__ char Alds[2][16384];
  __shared__ char Blds[2][16384];
  // XCD-chunked: blocks sharing an A row-tile (same rt) land on the same XCD
  int g = blockIdx.x;
  int xcd = g & 7, idx = g >> 3;
  int rt = xcd * 80 + idx / 6;                 // 640 row-tiles, 80 per XCD
  int ct = idx % 6;
  int mat = ct >> 1;
  int col0 = (ct & 1) * 128;

  int tid = threadIdx.x, w = tid >> 6, l = tid & 63;
  int wr = (w >> 1) * 64, wc = (w & 1) * 64;
  int hi16 = (l >> 4) * 16;

  const char* Ab = (const char*)A + (size_t)rt * 128 * 512;
  const char* Bb = (const char*)(WT + (size_t)mat * 65536) + (size_t)col0 * 512;

  auto STAGE = [&](int bufi, int s) {
    int k0b = s * 128;
#pragma unroll
    for (int j8 = 0; j8 < 4; ++j8) {
      int d = (j8 * 256 + tid) * 16;
      int row = d >> 7;
      int cx = (d & 127) ^ ((row & 7) << 4);
      glds16(Ab + (size_t)row * 512 + k0b + cx, Alds[bufi] + d);
      glds16(Bb + (size_t)row * 512 + k0b + cx, Blds[bufi] + d);
    }
  };

  f32x4 acc[4][4] = {};
  STAGE(0, 0);

  for (int s = 0; s < 4; ++s) {
    int cur = s & 1;
    if (s < 3) {
      STAGE(cur ^ 1, s + 1);
      asm volatile("s_waitcnt vmcnt(8)" ::: "memory");   // current stage's 8 loads landed
    } else {
      asm volatile("s_waitcnt vmcnt(0)" ::: "memory");
    }
    __builtin_amdgcn_sched_barrier(0);
    __builtin_amdgcn_s_barrier();
#pragma unroll
    for (int ks = 0; ks < 2; ++ks) {
      short8 a[4], bb[4];
#pragma unroll
      for (int i = 0; i < 4; ++i) {
        int ra = wr + 16 * i + (l & 15);
        a[i] = *(const short8*)(Alds[cur] + ra * 128 + ((ks * 64 + hi16) ^ ((ra & 7) << 4)));
        int rb = wc + 16 * i + (l & 15);
        bb[i] = *(const short8*)(Blds[cur] + rb * 128 + ((rb & 7) << 4 ^ (ks * 64 + hi16)));
      }
      __builtin_amdgcn_s_setprio(1);
#pragma unroll
      for (int i = 0; i < 4; ++i)
#pragma unroll
        for (int j = 0; j < 4; ++j)
          acc[i][j] = __builtin_amdgcn_mfma_f32_16x16x32_bf16(a[i], bb[j], acc[i][j], 0, 0, 0);
      __builtin_amdgcn_s_setprio(0);
    }
    asm volatile("s_waitcnt lgkmcnt(0)" ::: "memory");
    __builtin_amdgcn_sched_barrier(0);
    __builtin_amdgcn_s_barrier();                        // buffer free for next STAGE
  }

  // epilogue (direct stores): C/D layout col = lane&15, row = (lane>>4)*4 + r  [m89]
  if (mat < 2) {
    unsigned short* oq = qk + (size_t)mat * M_ * 256;
#pragma unroll
    for (int i = 0; i < 4; ++i)
#pragma unroll
      for (int j = 0; j < 4; ++j)
#pragma unroll
        for (int r = 0; r < 4; ++r) {
          int row = rt * 128 + wr + 16 * i + (l >> 4) * 4 + r;
          int col = col0 + wc + 16 * j + (l & 15);
          oq[(size_t)row * 256 + col] = f2bf(acc[i][j][r]);
        }
  } else {
    // V: write transposed vT[b][feat][s]; 4 acc rows = 4 consecutive s -> 8B store
#pragma unroll
    for (int i = 0; i < 4; ++i) {
      int row0 = rt * 128 + wr + 16 * i + (l >> 4) * 4;
      int b = row0 >> 12, s0 = row0 & 4095;
#pragma unroll
      for (int j = 0; j < 4; ++j) {
        int col = col0 + wc + 16 * j + (l & 15);
        us4 o;
#pragma unroll
        for (int r = 0; r < 4; ++r) o[r] = f2bf(acc[i][j][r]);
        *(us4*)(vT + ((size_t)(b * 256 + col) << 12) + s0) = o;
      }
    }
  }
}

// ---------------- K2: block-local attention + fused out-proj ----------------
// 1280 blocks: (b,n,half). 4 waves x 16 q-rows. Pipelined K/V phases (counted vmcnt);
// softmax without max-sub (|logit| < ~0.6, exact by shift-invariance); padded edge
// chunks contribute exp(0)=1 per key (dsum preinit). Epilogue: O -> LDS (bf16),
// O @ Wo + bias computed in-kernel (WoT staged from L2), fp32 out written at the
// permuted rows f = n*2560 + b*128 + half*64 + q (contiguous 64-row span).
__global__ __launch_bounds__(256, 2) void k_attn(const unsigned short* __restrict__ q,
                                                 const unsigned short* __restrict__ k,
                                                 const unsigned short* __restrict__ vT,
                                                 const unsigned short* __restrict__ WT,
                                                 const float* __restrict__ bo,
                                                 float* __restrict__ out) {
  __shared__ char kb2[2][32768];    // K [64][256] / Vt [256][64] / O [64][256] / WoT chunk
  __shared__ char pl[64 * 144];     // P [64 rows][64 keys] bf16, row stride 144 B

  int g = blockIdx.x;
  int xcd = g & 7, idx = g >> 3;                 // 160 per XCD
  int nbid = xcd * 80 + (idx >> 1);
  int half = idx & 1;
  int b = nbid >> 5, n = nbid & 31;
  int tid = threadIdx.x, w = tid >> 6, l = tid & 63;
  int hi16 = (l >> 4) * 16;

  int rowbase = b * 4096 + n * 128 + half * 64 + w * 16;
  const char* qrow = (const char*)q + (size_t)(rowbase + (l & 15)) * 512;
  short8 qf[8];
#pragma unroll
  for (int ks = 0; ks < 8; ++ks) qf[ks] = *(const short8*)(qrow + ks * 64 + hi16);

  f32x4 zero4 = {0.f, 0.f, 0.f, 0.f};
  f32x4 oacc[16];
#pragma unroll
  for (int fj = 0; fj < 16; ++fj) oacc[fj] = zero4;
  float einit = (n == 0 || n == 31) ? 8.0f : 0.0f;   // 2 padded chunks * 4 keys/lane
  float dsum[4] = {einit, einit, einit, einit};

  const char* kbase = (const char*)k + (size_t)b * 4096 * 512;
  const char* vtb   = (const char*)vT + (size_t)b * 256 * 8192;
  const char* woT   = (const char*)(WT + 3 * 65536);

  int c0 = (n == 0) ? 2 : 0;                     // valid chunk range (contiguous)
  int c1 = (n == 31) ? 3 : 5;
  int P = (c1 - c0 + 1) * 2;                     // 8 or 12 phases

  auto STAGE = [&](int bufi, int p) {
    int c = c0 + (p >> 1);
    int kg = (n + (c >> 1) - 1) * 128 + (c & 1) * 64;
    char* dst = kb2[bufi];
    if ((p & 1) == 0) {                          // K chunk: [64 keys][256 feats]
#pragma unroll
      for (int j8 = 0; j8 < 8; ++j8) {
        int d = (j8 * 256 + tid) * 16;
        int key = d >> 9;
        int f2 = (d & 511) ^ ((key & 7) << 4);
        glds16(kbase + (size_t)(kg + key) * 512 + f2, dst + d);
      }
    } else {                                     // Vt chunk: [256 feats][64 keys]
#pragma unroll
      for (int j8 = 0; j8 < 8; ++j8) {
        int d = (j8 * 256 + tid) * 16;
        int feat = d >> 7;
        int kx = (d & 127) ^ ((feat & 7) << 4);
        glds16(vtb + (size_t)feat * 8192 + (size_t)kg * 2 + kx, dst + d);
      }
    }
  };

  STAGE(0, 0);

  for (int p = 0; p < P; ++p) {
    int cur = p & 1;
    if (p + 1 < P) {
      STAGE(cur ^ 1, p + 1);
      asm volatile("s_waitcnt vmcnt(8)" ::: "memory");
    } else {
      asm volatile("s_waitcnt vmcnt(0)" ::: "memory");
    }
    __builtin_amdgcn_sched_barrier(0);
    __builtin_amdgcn_s_barrier();

    const char* kv = kb2[cur];
    if ((p & 1) == 0) {
      // QK^T /16, exp, denom, P -> LDS
#pragma unroll
      for (int j = 0; j < 4; ++j) {
        f32x4 s = zero4;
        int key = 16 * j + (l & 15);
        int kb0 = key * 512, km = (key & 7) << 4;
        __builtin_amdgcn_s_setprio(1);
#pragma unroll
        for (int ks = 0; ks < 8; ++ks) {
          short8 kf = *(const short8*)(kv + kb0 + ((ks * 64 + hi16) ^ km));
          s = __builtin_amdgcn_mfma_f32_16x16x32_bf16(qf[ks], kf, s, 0, 0, 0);
        }
        __builtin_amdgcn_s_setprio(0);
#pragma unroll
        for (int r = 0; r < 4; ++r) {
          float pv = __expf(s[r] * 0.0625f);
          dsum[r] += pv;
          int prow = w * 16 + (l >> 4) * 4 + r;
          *(unsigned short*)(pl + prow * 144 + key * 2) = f2bf(pv);
        }
      }
    } else {
      // O += P * V
#pragma unroll
      for (int ks2 = 0; ks2 < 2; ++ks2) {
        short8 pa = *(const short8*)(pl + (w * 16 + (l & 15)) * 144 + ks2 * 64 + hi16);
        __builtin_amdgcn_s_setprio(1);
#pragma unroll
        for (int fj = 0; fj < 16; ++fj) {
          int feat = 16 * fj + (l & 15);
          short8 vf = *(const short8*)(kv + feat * 128 + ((ks2 * 64 + hi16) ^ ((feat & 7) << 4)));
          oacc[fj] = __builtin_amdgcn_mfma_f32_16x16x32_bf16(pa, vf, oacc[fj], 0, 0, 0);
        }
        __builtin_amdgcn_s_setprio(0);
      }
    }
    asm volatile("s_waitcnt lgkmcnt(0)" ::: "memory");
    __builtin_amdgcn_sched_barrier(0);
    __builtin_amdgcn_s_barrier();
  }

  // ---- softmax denominator ----
#pragma unroll
  for (int r = 0; r < 4; ++r) {
    float t = dsum[r];
    t += __shfl_xor(t, 1); t += __shfl_xor(t, 2);
    t += __shfl_xor(t, 4); t += __shfl_xor(t, 8);
    dsum[r] = 1.0f / t;
  }

  // ---- fused out-proj: O(bf16) -> kb2[0]; WoT chunks -> kb2[1]; out = O@Wo + bo ----
  char* OL = kb2[0];
#pragma unroll
  for (int fj = 0; fj < 16; ++fj) {
    int c2 = 2 * (16 * fj + (l & 15));
#pragma unroll
    for (int r = 0; r < 4; ++r) {
      int qr = w * 16 + (l >> 4) * 4 + r;
      *(unsigned short*)(OL + qr * 512 + (c2 ^ ((qr & 7) << 4))) =
          f2bf(oacc[fj][r] * dsum[r]);
    }
  }

  auto STAGE_WO = [&](int kc) {                  // WoT[n][k] chunk: [256 n][128 B]
#pragma unroll
    for (int j8 = 0; j8 < 8; ++j8) {
      int d = (j8 * 256 + tid) * 16;
      int nrow = d >> 7;
      int kx = (d & 127) ^ ((nrow & 7) << 4);
      glds16(woT + (size_t)nrow * 512 + kc * 128 + kx, kb2[1] + d);
    }
  };

  f32x4 acc2[16];
#pragma unroll
  for (int j = 0; j < 16; ++j) acc2[j] = zero4;

  STAGE_WO(0);
  for (int kc = 0; kc < 4; ++kc) {
    asm volatile("s_waitcnt vmcnt(0)" ::: "memory");
    __builtin_amdgcn_sched_barrier(0);
    __builtin_amdgcn_s_barrier();
#pragma unroll
    for (int kstep = 0; kstep < 2; ++kstep) {
      int qr = w * 16 + (l & 15);
      short8 af = *(const short8*)(OL + qr * 512 +
                    ((kc * 128 + kstep * 64 + hi16) ^ ((qr & 7) << 4)));
      __builtin_amdgcn_s_setprio(1);
#pragma unroll
      for (int j = 0; j < 16; ++j) {
        int nr = 16 * j + (l & 15);
        short8 bf = *(const short8*)(kb2[1] + nr * 128 +
                      ((kstep * 64 + hi16) ^ ((nr & 7) << 4)));
        acc2[j] = __builtin_amdgcn_mfma_f32_16x16x32_bf16(af, bf, acc2[j], 0, 0, 0);
      }
      __builtin_amdgcn_s_setprio(0);
    }
    asm volatile("s_waitcnt lgkmcnt(0)" ::: "memory");
    __builtin_amdgcn_sched_barrier(0);
    __builtin_amdgcn_s_barrier();
    if (kc < 3) STAGE_WO(kc + 1);
  }

  // out rows f = n*2560 + b*128 + half*64 + q  (contiguous 64-row span)
  int f0 = n * 2560 + b * 128 + half * 64 + w * 16 + (l >> 4) * 4;
#pragma unroll
  for (int j = 0; j < 16; ++j) {
    int col = 16 * j + (l & 15);
    float bj = bo[col];
#pragma unroll
    for (int r = 0; r < 4; ++r)
      out[(size_t)(f0 + r) * 256 + col] = acc2[j][r] + bj;
  }
}

// ---------------- launch ----------------
extern "C" void kernel_launch(void* const* d_in, const int* in_sizes, int n_in,
                              void* d_out, int out_size, void* d_ws, size_t ws_size,
                              hipStream_t stream) {
  (void)in_sizes; (void)n_in; (void)out_size; (void)ws_size;
  const float* x  = (const float*)d_in[0];
  const float* Wq = (const float*)d_in[1];
  const float* Wk = (const float*)d_in[2];
  const float* Wv = (const float*)d_in[3];
  const float* Wo = (const float*)d_in[4];
  const float* bo = (const float*)d_in[5];

  char* ws = (char*)d_ws;
  unsigned short* xb = (unsigned short*)ws;
  unsigned short* qb = (unsigned short*)(ws + OFF_Q);
  unsigned short* kb = (unsigned short*)(ws + OFF_K);
  unsigned short* vT = (unsigned short*)(ws + OFF_V);
  unsigned short* WT = (unsigned short*)(ws + OFF_WT);

  k_convert_x<<<20480, 256, 0, stream>>>(x, xb);
  k_convert_w<<<64, 256, 0, stream>>>(Wq, Wk, Wv, Wo, WT);
  k_gemm<<<3840, 256, 0, stream>>>(xb, WT, qb, vT);          // q,k row-major; v -> vT
  k_attn<<<1280, 256, 0, stream>>>(qb, kb, vT, WT, bo, (float*)d_out);
}